// Round 3
// baseline (50.722 us; speedup 1.0000x reference)
//
#include <hip/hip_runtime.h>
#include <hip/hip_bf16.h>

// out[i] = sigmoid(row_avg[i] * w + b), N = 33554432 fp32.
// Streaming, memory-bound. Native vec4 + nontemporal hints + 2x unroll.

typedef float floatx4 __attribute__((ext_vector_type(4)));

__global__ void __launch_bounds__(256) sigmoid_linear_kernel(
    const float* __restrict__ x, const float* __restrict__ wp,
    const float* __restrict__ bp, float* __restrict__ out, int n4) {
    const float w = wp[0];
    const float b = bp[0];
    const floatx4* __restrict__ x4 = reinterpret_cast<const floatx4*>(x);
    floatx4* __restrict__ o4 = reinterpret_cast<floatx4*>(out);

    const int tid = blockIdx.x * blockDim.x + threadIdx.x;
    const int stride = gridDim.x * blockDim.x;

    // 2x unrolled grid-stride: two independent 16B loads in flight.
    int i = tid;
    for (; i + stride < n4; i += 2 * stride) {
        floatx4 v0 = __builtin_nontemporal_load(&x4[i]);
        floatx4 v1 = __builtin_nontemporal_load(&x4[i + stride]);
        floatx4 r0, r1;
        #pragma unroll
        for (int j = 0; j < 4; ++j) {
            r0[j] = 1.0f / (1.0f + __expf(-(v0[j] * w + b)));
            r1[j] = 1.0f / (1.0f + __expf(-(v1[j] * w + b)));
        }
        __builtin_nontemporal_store(r0, &o4[i]);
        __builtin_nontemporal_store(r1, &o4[i + stride]);
    }
    if (i < n4) {
        floatx4 v = __builtin_nontemporal_load(&x4[i]);
        floatx4 r;
        #pragma unroll
        for (int j = 0; j < 4; ++j)
            r[j] = 1.0f / (1.0f + __expf(-(v[j] * w + b)));
        __builtin_nontemporal_store(r, &o4[i]);
    }
}

extern "C" void kernel_launch(void* const* d_in, const int* in_sizes, int n_in,
                              void* d_out, int out_size, void* d_ws, size_t ws_size,
                              hipStream_t stream) {
    const float* x = (const float*)d_in[0];   // row_avg, [1, N] fp32
    const float* w = (const float*)d_in[1];   // [1,1]
    const float* b = (const float*)d_in[2];   // [1]
    float* out = (float*)d_out;               // [N] fp32

    const int n = in_sizes[0];                // 33554432
    const int n4 = n >> 2;

    const int block = 256;
    int grid = (n4 + block - 1) / block;
    if (grid > 2048) grid = 2048;

    sigmoid_linear_kernel<<<grid, block, 0, stream>>>(x, w, b, out, n4);
}

// Round 4
// 45.759 us; speedup vs baseline: 1.1085x; 1.1085x over previous
//
#include <hip/hip_runtime.h>
#include <hip/hip_bf16.h>

// out[i] = sigmoid(row_avg[i] * w + b), N = 33554432 fp32.
// Streaming, memory-bound. Temporal (cached) loads to exploit L3 residency
// across replays; nontemporal stores so the write stream doesn't evict
// the input from L2/L3.

typedef float floatx4 __attribute__((ext_vector_type(4)));

__global__ void __launch_bounds__(256) sigmoid_linear_kernel(
    const float* __restrict__ x, const float* __restrict__ wp,
    const float* __restrict__ bp, float* __restrict__ out, int n4) {
    const float w = wp[0];
    const float b = bp[0];
    const floatx4* __restrict__ x4 = reinterpret_cast<const floatx4*>(x);
    floatx4* __restrict__ o4 = reinterpret_cast<floatx4*>(out);

    const int tid = blockIdx.x * blockDim.x + threadIdx.x;
    const int stride = gridDim.x * blockDim.x;

    for (int i = tid; i < n4; i += stride) {
        floatx4 v = x4[i];                       // temporal: let L3 serve re-reads
        floatx4 r;
        #pragma unroll
        for (int j = 0; j < 4; ++j)
            r[j] = 1.0f / (1.0f + __expf(-(v[j] * w + b)));
        __builtin_nontemporal_store(r, &o4[i]);  // write stream: no cache allocate
    }
}

extern "C" void kernel_launch(void* const* d_in, const int* in_sizes, int n_in,
                              void* d_out, int out_size, void* d_ws, size_t ws_size,
                              hipStream_t stream) {
    const float* x = (const float*)d_in[0];   // row_avg, [1, N] fp32
    const float* w = (const float*)d_in[1];   // [1,1]
    const float* b = (const float*)d_in[2];   // [1]
    float* out = (float*)d_out;               // [N] fp32

    const int n = in_sizes[0];                // 33554432
    const int n4 = n >> 2;

    const int block = 256;
    int grid = (n4 + block - 1) / block;
    if (grid > 2048) grid = 2048;

    sigmoid_linear_kernel<<<grid, block, 0, stream>>>(x, w, b, out, n4);
}